// Round 10
// baseline (263.995 us; speedup 1.0000x reference)
//
#include <hip/hip_runtime.h>
#include <hip/hip_cooperative_groups.h>
#include <hip/hip_bf16.h>

namespace cg = cooperative_groups;

#define BB 16
#define NQ 64
#define NK 512
#define HD 256   // H = QS = KS = VD = 256

typedef __attribute__((ext_vector_type(8))) short short8;
typedef __attribute__((ext_vector_type(4))) float f32x4;

__device__ __forceinline__ ushort bf16_rne(float v) {
    unsigned u = __float_as_uint(v);
    return (ushort)((u + 0x7FFFu + ((u >> 16) & 1u)) >> 16);
}
__device__ __forceinline__ float bf16_to_f(ushort h) {
    return __uint_as_float(((unsigned)h) << 16);
}

// ---------------------------------------------------------------------------
// ONE cooperative kernel: proj -> grid.sync -> score -> grid.sync -> pv.
// 512 blocks x 256 thr (2 blocks/CU; LDS union 32 KB; VGPR cap 256 -> no
// spill).  Kills both inter-kernel gaps + 2 dispatch overheads, and makes
// the whole pipeline ONE dispatch whose counters are finally visible above
// the harness fill wall (every split kernel sat just under ~42us for 9
// rounds).  Phase bodies are the round-9 kernels nearly verbatim.
// ---------------------------------------------------------------------------
__global__ __launch_bounds__(256, 2) void fused_all(
    const float* __restrict__ queries, const float* __restrict__ keys,
    const float* __restrict__ values,  const int* __restrict__ vlens,
    const float* __restrict__ W_q,     const float* __restrict__ W_k,
    const float* __restrict__ w_v,
    float* __restrict__ qp, float* __restrict__ kp,
    float* __restrict__ Pt, float* __restrict__ out, float scale)
{
    __shared__ __align__(16) union {
        struct { ushort AsH[4096], AsL[4096], BsH[4096], BsL[4096]; } p; // 32KB
        struct { float eq[8][260]; float wv[HD]; } s;                    // 9.3KB
        struct { f32x4 red[128]; float Lred[8]; } v;                     // 2.1KB
    } u;

    const int bid = blockIdx.x;
    const int t = threadIdx.x, lane = t & 63, wave = t >> 6;
    cg::grid_group grid = cg::this_grid();

    // ===================== PHASE P: projection GEMM =====================
    // 576 tiles over 512 blocks (64 blocks take 2).  Fused A- and W-
    // conversion to hi/lo bf16; C = AhWh + AlWh + AhWl; epilogue exp2.
    for (int tile = bid; tile < 576; tile += 512) {
        const int bx = tile % 144;
        const int cols0 = (tile / 144) * 64;
        const float* A; const float* W; float* C; int rows0;
        if (bx < 16) { A = queries; W = W_q; C = qp; rows0 = bx * 64; }
        else         { A = keys;    W = W_k; C = kp; rows0 = (bx - 16) * 64; }

        const int quad = lane >> 4, l15 = lane & 15;
        const int sr  = t >> 2;
        const int sc2 = (t & 3) * 2;

        f32x4 acc[4];
        #pragma unroll
        for (int j = 0; j < 4; ++j) acc[j] = (f32x4){0.f, 0.f, 0.f, 0.f};

        for (int k0 = 0; k0 < 256; k0 += 64) {
            const float* arow = &A[(size_t)(rows0 + sr) * 256 + k0 + sc2 * 8];
            float4 a0 = *(const float4*)&arow[0];
            float4 a1 = *(const float4*)&arow[4];
            float4 a2 = *(const float4*)&arow[8];
            float4 a3 = *(const float4*)&arow[12];
            float wvv[16];
            {
                const float* wsrc = &W[(size_t)(k0 + sc2 * 8) * 256 + cols0 + sr];
                #pragma unroll
                for (int e = 0; e < 16; ++e)
                    wvv[e] = wsrc[(size_t)e * 256];
            }

            __syncthreads();   // previous tile/k0 compute done

            float av[16] = {a0.x, a0.y, a0.z, a0.w, a1.x, a1.y, a1.z, a1.w,
                            a2.x, a2.y, a2.z, a2.w, a3.x, a3.y, a3.z, a3.w};
            short8 ah0, ah1, al0, al1, bh0, bh1, bl0, bl1;
            #pragma unroll
            for (int e = 0; e < 8; ++e) {
                ushort h0 = bf16_rne(av[e]);
                ushort h1 = bf16_rne(av[8 + e]);
                ah0[e] = (short)h0;
                ah1[e] = (short)h1;
                al0[e] = (short)bf16_rne(av[e] - bf16_to_f(h0));
                al1[e] = (short)bf16_rne(av[8 + e] - bf16_to_f(h1));
                ushort w0 = bf16_rne(wvv[e]);
                ushort w1 = bf16_rne(wvv[8 + e]);
                bh0[e] = (short)w0;
                bh1[e] = (short)w1;
                bl0[e] = (short)bf16_rne(wvv[e] - bf16_to_f(w0));
                bl1[e] = (short)bf16_rne(wvv[8 + e] - bf16_to_f(w1));
            }
            {
                int s0 = sr * 8 + ((sc2 + 0) ^ (sr & 7));
                int s1 = sr * 8 + ((sc2 + 1) ^ (sr & 7));
                *(short8*)&u.p.AsH[s0 * 8] = ah0;
                *(short8*)&u.p.AsH[s1 * 8] = ah1;
                *(short8*)&u.p.AsL[s0 * 8] = al0;
                *(short8*)&u.p.AsL[s1 * 8] = al1;
                *(short8*)&u.p.BsH[s0 * 8] = bh0;
                *(short8*)&u.p.BsH[s1 * 8] = bh1;
                *(short8*)&u.p.BsL[s0 * 8] = bl0;
                *(short8*)&u.p.BsL[s1 * 8] = bl1;
            }
            __syncthreads();

            #pragma unroll
            for (int ks = 0; ks < 2; ++ks) {
                const int c = ks * 4 + quad;
                short8 aH, aL, bH[4], bL[4];
                {
                    int r = wave * 16 + l15;
                    int slot = r * 8 + (c ^ (r & 7));
                    aH = *(const short8*)&u.p.AsH[slot * 8];
                    aL = *(const short8*)&u.p.AsL[slot * 8];
                }
                #pragma unroll
                for (int ns = 0; ns < 4; ++ns) {
                    int n = ns * 16 + l15;
                    int slot = n * 8 + (c ^ (n & 7));
                    bH[ns] = *(const short8*)&u.p.BsH[slot * 8];
                    bL[ns] = *(const short8*)&u.p.BsL[slot * 8];
                }
                #pragma unroll
                for (int ns = 0; ns < 4; ++ns)
                    acc[ns] = __builtin_amdgcn_mfma_f32_16x16x32_bf16(aH, bH[ns], acc[ns], 0, 0, 0);
                #pragma unroll
                for (int ns = 0; ns < 4; ++ns)
                    acc[ns] = __builtin_amdgcn_mfma_f32_16x16x32_bf16(aL, bH[ns], acc[ns], 0, 0, 0);
                #pragma unroll
                for (int ns = 0; ns < 4; ++ns)
                    acc[ns] = __builtin_amdgcn_mfma_f32_16x16x32_bf16(aH, bL[ns], acc[ns], 0, 0, 0);
            }
        }

        const int rbase = rows0 + wave * 16 + quad * 4;
        #pragma unroll
        for (int ns = 0; ns < 4; ++ns) {
            int col = cols0 + ns * 16 + l15;
            #pragma unroll
            for (int r = 0; r < 4; ++r)
                C[(size_t)(rbase + r) * 256 + col] =
                    __builtin_amdgcn_exp2f(acc[ns][r] * scale);
        }
    }

    grid.sync();   // qp/kp complete + LDS repurpose safe

    // ===================== PHASE S: scores -> Pt =====================
    // 1024 tasks (b,qt8,seg8): exactly 2 per block.  Dead segs zero-fill
    // Pt so phase V's static 512-key loop is exact.
    for (int r = 0; r < 2; ++r) {
        const int task = bid * 2 + r;
        const int b   = task & 15;
        const int qt  = (task >> 4) & 7;
        const int seg = task >> 7;
        const int vl  = vlens[b];

        const int key = wave * 16 + (lane >> 2);
        const int ch  = lane & 3;
        const int kg  = seg * 64 + key;

        if (seg * 64 >= vl) {
            if (ch == 0) {
                float* dst = &Pt[((size_t)b * NK + kg) * 64 + qt * 8];
                *(float4*)&dst[0] = make_float4(0.f, 0.f, 0.f, 0.f);
                *(float4*)&dst[4] = make_float4(0.f, 0.f, 0.f, 0.f);
            }
            continue;
        }

        const float* krow = kp + ((size_t)b * NK + kg) * HD + ch * 4;
        float4 ek[16];
        #pragma unroll
        for (int j = 0; j < 16; ++j) ek[j] = *(const float4*)&krow[j * 16];

        const float* qsrc = qp + ((size_t)b * NQ + qt * 8) * HD;
        #pragma unroll
        for (int i = 0; i < 2; ++i) {
            int idx = i * 256 + t;
            int row = idx >> 6, c4 = (idx & 63) * 4;
            *(float4*)&u.s.eq[row][c4] = *(const float4*)&qsrc[(size_t)row * HD + c4];
        }
        if (t < 64) *(float4*)&u.s.wv[t * 4] = *(const float4*)&w_v[t * 4];
        __syncthreads();

        float Wsum;
        {
            float ws = u.s.wv[lane] + u.s.wv[lane + 64] +
                       u.s.wv[lane + 128] + u.s.wv[lane + 192];
            #pragma unroll
            for (int off = 32; off; off >>= 1) ws += __shfl_xor(ws, off);
            Wsum = ws;
        }

        float s[8] = {0.f, 0.f, 0.f, 0.f, 0.f, 0.f, 0.f, 0.f};
        #pragma unroll
        for (int j = 0; j < 16; ++j) {
            const int h = j * 16 + ch * 4;
            float4 e4 = ek[j];
            float4 w4 = *(const float4*)&u.s.wv[h];
            #pragma unroll
            for (int qi = 0; qi < 8; ++qi) {
                float4 q4 = *(const float4*)&u.s.eq[qi][h];
                float p0 = fmaf(q4.x, e4.x, 1.f);
                float p1 = fmaf(q4.y, e4.y, 1.f);
                float p2 = fmaf(q4.z, e4.z, 1.f);
                float p3 = fmaf(q4.w, e4.w, 1.f);
                float d01 = p0 * p1;
                float d23 = p2 * p3;
                float n01 = fmaf(w4.x, p1, w4.y * p0);
                float n23 = fmaf(w4.z, p3, w4.w * p2);
                float num = fmaf(d01, n23, d23 * n01);
                float rr  = __builtin_amdgcn_rcpf(d01 * d23);
                s[qi] = fmaf(num, rr, s[qi]);
            }
        }
        #pragma unroll
        for (int qi = 0; qi < 8; ++qi) {
            s[qi] += __shfl_xor(s[qi], 1);
            s[qi] += __shfl_xor(s[qi], 2);
        }

        if (ch == 0) {
            const bool masked = (kg >= vl);
            const float L2E = 1.4426950408889634f;
            float pt[8];
            #pragma unroll
            for (int qi = 0; qi < 8; ++qi) {
                float sv = fmaf(-2.f, s[qi], Wsum);      // |score| <= ~13
                pt[qi] = masked ? 0.f : __builtin_amdgcn_exp2f(sv * L2E);
            }
            float* dst = &Pt[((size_t)b * NK + kg) * 64 + qt * 8];
            *(float4*)&dst[0] = make_float4(pt[0], pt[1], pt[2], pt[3]);
            *(float4*)&dst[4] = make_float4(pt[4], pt[5], pt[6], pt[7]);
        }
        __syncthreads();   // eq WAR before next task
    }

    grid.sync();   // Pt complete + LDS repurpose safe

    // ===================== PHASE V: O = P.V / L =====================
    // 512 tasks: exactly 1 per block.  Static branch-free 512-key loop
    // (p = 0 beyond vl -> exact), unroll 16 -> 32 loads in flight.
    {
        const int b   = bid & 15;
        const int qt  = (bid >> 4) & 7;
        const int vdq = bid >> 7;

        const int vd4 = t & 15;
        const int q   = (t >> 4) & 7;
        const int kp2 = t >> 7;

        const float* vptr = values + (size_t)b * NK * HD + vdq * 64 + vd4 * 4;
        const float* pptr = Pt + (size_t)b * NK * 64 + qt * 8 + q;

        f32x4 acc = (f32x4){0.f, 0.f, 0.f, 0.f};
        float Lacc = 0.f;
        #pragma unroll 16
        for (int i = 0; i < NK / 2; ++i) {
            const int k = kp2 + 2 * i;
            float  p = pptr[(size_t)k * 64];
            float4 v = *(const float4*)&vptr[(size_t)k * HD];
            acc[0] = fmaf(p, v.x, acc[0]);
            acc[1] = fmaf(p, v.y, acc[1]);
            acc[2] = fmaf(p, v.z, acc[2]);
            acc[3] = fmaf(p, v.w, acc[3]);
            Lacc += p;
        }

        if (kp2 == 1) {
            u.v.red[t - 128] = acc;
            if (vd4 == 0) u.v.Lred[q] = Lacc;
        }
        __syncthreads();
        if (kp2 == 0) {
            f32x4 o = u.v.red[t];
            acc[0] += o[0]; acc[1] += o[1]; acc[2] += o[2]; acc[3] += o[3];
            float L = Lacc + u.v.Lred[q];
            float rr = __builtin_amdgcn_rcpf(L);
            float4 ov = make_float4(acc[0] * rr, acc[1] * rr,
                                    acc[2] * rr, acc[3] * rr);
            *(float4*)&out[((size_t)(b * 64 + qt * 8 + q)) * 256 + vdq * 64 + vd4 * 4] = ov;
        }
    }
}

extern "C" void kernel_launch(void* const* d_in, const int* in_sizes, int n_in,
                              void* d_out, int out_size, void* d_ws, size_t ws_size,
                              hipStream_t stream) {
    const float* queries = (const float*)d_in[0];
    const float* keys    = (const float*)d_in[1];
    const float* values  = (const float*)d_in[2];
    const int*   vlens   = (const int*)d_in[3];
    const float* W_q     = (const float*)d_in[4];
    const float* W_k     = (const float*)d_in[5];
    const float* w_v     = (const float*)d_in[6];
    float* out = (float*)d_out;

    // ws layout (~11 MB of 256 MiB):
    float* kp = (float*)d_ws;                            // 8 MB
    float* qp = kp + (size_t)BB * NK * HD;               // 1 MB
    float* Pt = qp + (size_t)BB * NQ * HD;               // 2 MB  [B][NK][64]

    float SC = 2.885390081777927f;                       // 2/ln(2)

    void* args[] = {
        (void*)&queries, (void*)&keys, (void*)&values, (void*)&vlens,
        (void*)&W_q, (void*)&W_k, (void*)&w_v,
        (void*)&qp, (void*)&kp, (void*)&Pt, (void*)&out, (void*)&SC,
    };
    hipLaunchCooperativeKernel((void*)fused_all, dim3(512), dim3(256),
                               args, 0, stream);
}

// Round 12
// 111.808 us; speedup vs baseline: 2.3611x; 2.3611x over previous
//
#include <hip/hip_runtime.h>
#include <hip/hip_bf16.h>

#define BB 16
#define NQ 64
#define NK 512
#define HD 256   // H = QS = KS = VD = 256

typedef __attribute__((ext_vector_type(8))) short short8;
typedef __attribute__((ext_vector_type(4))) float f32x4;

__device__ __forceinline__ ushort bf16_rne(float v) {
    unsigned u = __float_as_uint(v);
    return (ushort)((u + 0x7FFFu + ((u >> 16) & 1u)) >> 16);
}
__device__ __forceinline__ float bf16_to_f(ushort h) {
    return __uint_as_float(((unsigned)h) << 16);
}

// ---------------------------------------------------------------------------
// Projection GEMM with FUSED A- and W-conversion (proven in rounds 8-9,
// bit-identical to the old wconv+proj path).  epilogue exp2(acc*scale):
// score kernel consumes EQ=e^{2q}, EK=e^{2k} directly.
// ---------------------------------------------------------------------------
__global__ __launch_bounds__(256, 2) void proj_fused2(
    const float* __restrict__ queries, const float* __restrict__ keys,
    const float* __restrict__ W_q, const float* __restrict__ W_k,
    float* __restrict__ qp, float* __restrict__ kp, float scale)
{
    __shared__ ushort AsH[64 * 64], AsL[64 * 64];
    __shared__ ushort BsH[64 * 64], BsL[64 * 64];

    const float* A; const float* W; float* C; int rows0;
    const int bx = blockIdx.x;
    if (bx < 16) { A = queries; W = W_q; C = qp; rows0 = bx * 64; }
    else         { A = keys;    W = W_k; C = kp; rows0 = (bx - 16) * 64; }
    const int cols0 = blockIdx.y * 64;

    const int t = threadIdx.x, lane = t & 63, wave = t >> 6;
    const int quad = lane >> 4, l15 = lane & 15;
    const int sr  = t >> 2;
    const int sc2 = (t & 3) * 2;

    f32x4 acc[4];
    #pragma unroll
    for (int j = 0; j < 4; ++j) acc[j] = (f32x4){0.f, 0.f, 0.f, 0.f};

    for (int k0 = 0; k0 < 256; k0 += 64) {
        const float* arow = &A[(size_t)(rows0 + sr) * 256 + k0 + sc2 * 8];
        float4 a0 = *(const float4*)&arow[0];
        float4 a1 = *(const float4*)&arow[4];
        float4 a2 = *(const float4*)&arow[8];
        float4 a3 = *(const float4*)&arow[12];
        float wvv[16];
        {
            const float* wsrc = &W[(size_t)(k0 + sc2 * 8) * 256 + cols0 + sr];
            #pragma unroll
            for (int e = 0; e < 16; ++e)
                wvv[e] = wsrc[(size_t)e * 256];
        }

        __syncthreads();   // previous tile's compute done

        float av[16] = {a0.x, a0.y, a0.z, a0.w, a1.x, a1.y, a1.z, a1.w,
                        a2.x, a2.y, a2.z, a2.w, a3.x, a3.y, a3.z, a3.w};
        short8 ah0, ah1, al0, al1, bh0, bh1, bl0, bl1;
        #pragma unroll
        for (int e = 0; e < 8; ++e) {
            ushort h0 = bf16_rne(av[e]);
            ushort h1 = bf16_rne(av[8 + e]);
            ah0[e] = (short)h0;
            ah1[e] = (short)h1;
            al0[e] = (short)bf16_rne(av[e] - bf16_to_f(h0));
            al1[e] = (short)bf16_rne(av[8 + e] - bf16_to_f(h1));
            ushort w0 = bf16_rne(wvv[e]);
            ushort w1 = bf16_rne(wvv[8 + e]);
            bh0[e] = (short)w0;
            bh1[e] = (short)w1;
            bl0[e] = (short)bf16_rne(wvv[e] - bf16_to_f(w0));
            bl1[e] = (short)bf16_rne(wvv[8 + e] - bf16_to_f(w1));
        }
        {
            int s0 = sr * 8 + ((sc2 + 0) ^ (sr & 7));
            int s1 = sr * 8 + ((sc2 + 1) ^ (sr & 7));
            *(short8*)&AsH[s0 * 8] = ah0;
            *(short8*)&AsH[s1 * 8] = ah1;
            *(short8*)&AsL[s0 * 8] = al0;
            *(short8*)&AsL[s1 * 8] = al1;
            *(short8*)&BsH[s0 * 8] = bh0;
            *(short8*)&BsH[s1 * 8] = bh1;
            *(short8*)&BsL[s0 * 8] = bl0;
            *(short8*)&BsL[s1 * 8] = bl1;
        }
        __syncthreads();

        #pragma unroll
        for (int ks = 0; ks < 2; ++ks) {
            const int c = ks * 4 + quad;
            short8 aH, aL, bH[4], bL[4];
            {
                int r = wave * 16 + l15;
                int slot = r * 8 + (c ^ (r & 7));
                aH = *(const short8*)&AsH[slot * 8];
                aL = *(const short8*)&AsL[slot * 8];
            }
            #pragma unroll
            for (int ns = 0; ns < 4; ++ns) {
                int n = ns * 16 + l15;
                int slot = n * 8 + (c ^ (n & 7));
                bH[ns] = *(const short8*)&BsH[slot * 8];
                bL[ns] = *(const short8*)&BsL[slot * 8];
            }
            #pragma unroll
            for (int ns = 0; ns < 4; ++ns)
                acc[ns] = __builtin_amdgcn_mfma_f32_16x16x32_bf16(aH, bH[ns], acc[ns], 0, 0, 0);
            #pragma unroll
            for (int ns = 0; ns < 4; ++ns)
                acc[ns] = __builtin_amdgcn_mfma_f32_16x16x32_bf16(aL, bH[ns], acc[ns], 0, 0, 0);
            #pragma unroll
            for (int ns = 0; ns < 4; ++ns)
                acc[ns] = __builtin_amdgcn_mfma_f32_16x16x32_bf16(aH, bL[ns], acc[ns], 0, 0, 0);
        }
    }

    const int rbase = rows0 + wave * 16 + quad * 4;
    #pragma unroll
    for (int ns = 0; ns < 4; ++ns) {
        int col = cols0 + ns * 16 + l15;
        #pragma unroll
        for (int r = 0; r < 4; ++r)
            C[(size_t)(rbase + r) * 256 + col] =
                __builtin_amdgcn_exp2f(acc[ns][r] * scale);
    }
}

// ---------------------------------------------------------------------------
// Segment flash partial (round-4's best-measured monolith, qtile=8, 8 waves
// = (kq, hh)), launch_bounds (512,4): VGPR cap 128 (the R4 (512,6) cap of
// 85 forced hot-loop spills: ek[8]=32 + vv[4]=16 + acc=16 + s=8 + addrs).
// Residency stays LDS-limited (45 KB -> 2-3 blocks/CU) either way.
// ROUND-11 BUG FIXED: ek loads stride j*16 (matching h = hh*128 + j*16 +
// ch*4), not j*32.  Math now bit-identical to validated round 4.
// ---------------------------------------------------------------------------
__global__ __launch_bounds__(512, 4) void score_pv_seg5(
    const float* __restrict__ qp,      // [B*NQ, H]  EQ = exp2(q * 2/ln2)
    const float* __restrict__ kp,      // [B*NK, H]  EK = exp2(k * 2/ln2)
    const float* __restrict__ values,  // [B, NK, VD]
    const int*   __restrict__ vlens,   // [B]
    const float* __restrict__ w_v,     // [H]
    float* __restrict__ pO,            // [B][8qt][8seg][8q][256]
    float* __restrict__ pL)            // [B][8qt][8seg][8q]
{
    __shared__ float eq[8][260];
    __shared__ float wv[HD];
    __shared__ float Ps[8][66];
    __shared__ float sP[8][66];
    __shared__ float part[4][8][260];

    const int b   = blockIdx.x & 15;
    const int qt  = blockIdx.x >> 4;    // 0..7
    const int seg = blockIdx.y;         // 0..7
    const int vl  = vlens[b];
    if (seg * 64 >= vl) return;

    const int t = threadIdx.x, lane = t & 63, wave = t >> 6;  // wave 0..7
    const int kq = wave & 3;            // key quarter
    const int hh = wave >> 2;           // h half
    const int key = kq * 16 + (lane >> 2);   // 0..63
    const int ch  = lane & 3;
    const int kg  = seg * 64 + key;

    // ---- issue this wave's 8 ek loads (latency overlaps eq staging) ----
    // ek[j] covers h = hh*128 + j*16 + ch*4 .. +3   (stride 16 floats!)
    const float* krow = kp + ((size_t)b * NK + kg) * HD + hh * 128 + ch * 4;
    float4 ek[8];
    #pragma unroll
    for (int j = 0; j < 8; ++j) ek[j] = *(const float4*)&krow[j * 16];

    // ---- stage EQ (8 rows x 256): exactly one float4 per thread ----
    const float* qsrc = qp + ((size_t)b * NQ + qt * 8) * HD;
    {
        int row = t >> 6, c4 = (t & 63) * 4;
        *(float4*)&eq[row][c4] = *(const float4*)&qsrc[(size_t)row * HD + c4];
    }
    if (t < 64) *(float4*)&wv[t * 4] = *(const float4*)&w_v[t * 4];
    __syncthreads();

    // Wsum (redundant per wave, parallel)
    float Wsum;
    {
        float ws = wv[lane] + wv[lane + 64] + wv[lane + 128] + wv[lane + 192];
        #pragma unroll
        for (int off = 32; off; off >>= 1) ws += __shfl_xor(ws, off);
        Wsum = ws;
    }

    // ---- scores over this wave's h-half: 4-way grouped reciprocal ----
    float s[8] = {0.f, 0.f, 0.f, 0.f, 0.f, 0.f, 0.f, 0.f};
    #pragma unroll
    for (int j = 0; j < 8; ++j) {
        const int h = hh * 128 + j * 16 + ch * 4;
        float4 e4 = ek[j];
        float4 w4 = *(const float4*)&wv[h];
        #pragma unroll
        for (int qi = 0; qi < 8; ++qi) {
            float4 q4 = *(const float4*)&eq[qi][h];   // LDS broadcast (EQ)
            float p0 = fmaf(q4.x, e4.x, 1.f);
            float p1 = fmaf(q4.y, e4.y, 1.f);
            float p2 = fmaf(q4.z, e4.z, 1.f);
            float p3 = fmaf(q4.w, e4.w, 1.f);
            float d01 = p0 * p1;
            float d23 = p2 * p3;
            float n01 = fmaf(w4.x, p1, w4.y * p0);
            float n23 = fmaf(w4.z, p3, w4.w * p2);
            float num = fmaf(d01, n23, d23 * n01);
            float r   = __builtin_amdgcn_rcpf(d01 * d23);
            s[qi] = fmaf(num, r, s[qi]);
        }
    }
    #pragma unroll
    for (int qi = 0; qi < 8; ++qi) {
        s[qi] += __shfl_xor(s[qi], 1);
        s[qi] += __shfl_xor(s[qi], 2);
    }
    if (hh == 1 && ch == 0) {
        #pragma unroll
        for (int qi = 0; qi < 8; ++qi) sP[qi][key] = s[qi];
    }
    __syncthreads();
    // ---- no-max: Ps = e^{score} directly; masked -> exact 0 ----
    const float L2E = 1.4426950408889634f;
    if (hh == 0 && ch == 0) {
        const bool masked = (kg >= vl);
        #pragma unroll
        for (int qi = 0; qi < 8; ++qi) {
            float sv = fmaf(-2.f, s[qi] + sP[qi][key], Wsum);
            Ps[qi][key] = masked ? 0.f : __builtin_amdgcn_exp2f(sv * L2E);
        }
    }
    __syncthreads();

    // ---- issue first 4 v loads; latency hides under the pL reduce ----
    const float* vbase = values + ((size_t)b * NK + seg * 64 + kq * 16) * HD;
    float4 vv[4];
    #pragma unroll
    for (int i = 0; i < 4; ++i)
        vv[i] = *(const float4*)&vbase[(size_t)i * HD + lane * 4];

    // ---- pL row sums: wave w reduces row w ----
    {
        float l = Ps[wave][lane];
        #pragma unroll
        for (int off = 32; off; off >>= 1) l += __shfl_xor(l, off);
        if (lane == 0)
            pL[(((size_t)(b * 8 + qt) * 8 + seg)) * 8 + wave] = l;
    }

    // ---- PV: wave (kq,hh) -> 16 keys x 4 q-rows; depth-4 v ring ----
    f32x4 acc[4];
    #pragma unroll
    for (int r = 0; r < 4; ++r) acc[r] = (f32x4){0.f, 0.f, 0.f, 0.f};
    #pragma unroll
    for (int i = 0; i < 16; ++i) {
        float4 v = vv[i & 3];
        if (i + 4 < 16)
            vv[i & 3] = *(const float4*)&vbase[(size_t)(i + 4) * HD + lane * 4];
        #pragma unroll
        for (int r = 0; r < 4; ++r) {
            float p = Ps[hh * 4 + r][kq * 16 + i];    // LDS broadcast
            acc[r][0] = fmaf(p, v.x, acc[r][0]);
            acc[r][1] = fmaf(p, v.y, acc[r][1]);
            acc[r][2] = fmaf(p, v.z, acc[r][2]);
            acc[r][3] = fmaf(p, v.w, acc[r][3]);
        }
    }
    #pragma unroll
    for (int r = 0; r < 4; ++r)
        *(f32x4*)&part[kq][hh * 4 + r][lane * 4] = acc[r];
    __syncthreads();

    // ---- cross-wave reduce + store partials (512 thr, one float4 each) ----
    const size_t ob = (((size_t)(b * 8 + qt) * 8 + seg)) * 8 * 256;
    {
        int qi = t >> 6, c4 = (t & 63) * 4;
        float4 p0 = *(const float4*)&part[0][qi][c4];
        float4 p1 = *(const float4*)&part[1][qi][c4];
        float4 p2 = *(const float4*)&part[2][qi][c4];
        float4 p3 = *(const float4*)&part[3][qi][c4];
        float4 o;
        o.x = (p0.x + p1.x) + (p2.x + p3.x);
        o.y = (p0.y + p1.y) + (p2.y + p3.y);
        o.z = (p0.z + p1.z) + (p2.z + p3.z);
        o.w = (p0.w + p1.w) + (p2.w + p3.w);
        *(float4*)&pO[ob + (size_t)qi * 256 + c4] = o;
    }
}

// ---------------------------------------------------------------------------
// Combine (no-max): O = sum_i pO_i / sum_i pL_i, i < nc.  Pure adds + 1 rcp.
// ---------------------------------------------------------------------------
__global__ __launch_bounds__(256) void combine_seg3(
    const float* __restrict__ pO, const float* __restrict__ pL,
    const int* __restrict__ vlens, float* __restrict__ out)
{
    const int b  = blockIdx.x >> 6;
    const int q  = blockIdx.x & 63;
    const int t  = threadIdx.x;
    const int nc = (vlens[b] + 63) >> 6;
    const int qt = q >> 3, qi = q & 7;

    const size_t base = (size_t)(b * 8 + qt) * 8;

    float L = 0.f, acc = 0.f;
    #pragma unroll
    for (int i = 0; i < 8; ++i) {
        if (i < nc) {
            L   += pL[(base + i) * 8 + qi];
            acc += pO[((base + i) * 8 + qi) * 256 + t];
        }
    }
    out[((size_t)(b * 64 + q)) * 256 + t] = acc * __builtin_amdgcn_rcpf(L);
}

extern "C" void kernel_launch(void* const* d_in, const int* in_sizes, int n_in,
                              void* d_out, int out_size, void* d_ws, size_t ws_size,
                              hipStream_t stream) {
    const float* queries = (const float*)d_in[0];
    const float* keys    = (const float*)d_in[1];
    const float* values  = (const float*)d_in[2];
    const int*   vlens   = (const int*)d_in[3];
    const float* W_q     = (const float*)d_in[4];
    const float* W_k     = (const float*)d_in[5];
    const float* w_v     = (const float*)d_in[6];
    float* out = (float*)d_out;

    // ws layout (~17.1 MB of 256 MiB):
    float* kp = (float*)d_ws;                            // 8 MB
    float* qp = kp + (size_t)BB * NK * HD;               // 1 MB
    float* pO = qp + (size_t)BB * NQ * HD;               // 8 MB
    float* pL = pO + (size_t)BB * 8 * 8 * 8 * 256;       // 32 KB

    const float SC = 2.885390081777927f;                 // 2/ln(2)

    proj_fused2<<<dim3(144, 4), 256, 0, stream>>>(queries, keys, W_q, W_k,
                                                  qp, kp, SC);
    score_pv_seg5<<<dim3(128, 8), 512, 0, stream>>>(qp, kp, values, vlens, w_v,
                                                    pO, pL);
    combine_seg3<<<dim3(BB * NQ), 256, 0, stream>>>(pO, pL, vlens, out);
}